// Round 1
// baseline (134.620 us; speedup 1.0000x reference)
//
#include <hip/hip_runtime.h>
#include <hip/hip_bf16.h>

#define SUBS  64
#define THIST 200

using bf16 = __hip_bfloat16;

// ---------------------------------------------------------------------------
// Kernel 1: kern_t[k*64+s] = sum_b (t/tau_b) exp(-t/tau_b) * K[s,b],
//           t = max(k - delta_s, 0), tau_b = exp(tau_spike[b]).
// Stored transposed [THIST][SUBS] as bf16.
// ---------------------------------------------------------------------------
__global__ __launch_bounds__(256) void k_kernels(
    const float* __restrict__ K_spike, const float* __restrict__ tau_spike,
    const float* __restrict__ delta_spike, bf16* __restrict__ kt)
{
    int idx = blockIdx.x * 256 + threadIdx.x;
    if (idx >= THIST * SUBS) return;
    int k = idx >> 6, s = idx & 63;
    float t = fmaxf((float)k - delta_spike[s], 0.0f);
    float v = 0.0f;
    #pragma unroll
    for (int b = 0; b < 3; ++b) {
        float tau = __expf(tau_spike[b]);
        float tt  = t / tau;
        v = fmaf(tt * __expf(-tt), K_spike[s * 3 + b], v);
    }
    kt[k * SUBS + s] = __float2bfloat16(v);
}

// ---------------------------------------------------------------------------
// Kernel 2: Zc = Z @ C^T (exact in bf16: 0/1 inputs, small-int sums)
//           base = S + theta + Y @ C^T   (bf16)
// 64-row tiles, LDS staging, 4x4 register micro-tiles.
// ---------------------------------------------------------------------------
__global__ __launch_bounds__(256) void k_zc_base(
    const float* __restrict__ Z, const float* __restrict__ Y,
    const float* __restrict__ S, const float* __restrict__ C,
    const float* __restrict__ theta,
    bf16* __restrict__ Zc, bf16* __restrict__ base, int T)
{
    __shared__ float Ct[SUBS * 65];   // Ct[j*65+s] = C[s][j]
    __shared__ float Zt[SUBS * 65];   // Zt[r*65+j]
    __shared__ float Yt[SUBS * 65];
    const int tid = threadIdx.x;
    const int t0  = blockIdx.x * 64;

    for (int idx = tid; idx < SUBS * SUBS; idx += 256) {
        int s = idx >> 6, j = idx & 63;
        Ct[j * 65 + s] = C[idx];
    }
    for (int idx = tid; idx < SUBS * SUBS; idx += 256) {
        int r = idx >> 6, c = idx & 63;
        int t = t0 + r;
        float z = 0.f, y = 0.f;
        if (t < T) { z = Z[(size_t)t * SUBS + c]; y = Y[(size_t)t * SUBS + c]; }
        Zt[r * 65 + c] = z;
        Yt[r * 65 + c] = y;
    }
    __syncthreads();

    const int tx = tid & 15, ty = tid >> 4;   // 16x16 threads, 4x4 micro-tile
    float az[4][4] = {}, ay[4][4] = {};
    #pragma unroll 4
    for (int j = 0; j < 64; ++j) {
        float zr[4], yr[4], cc[4];
        #pragma unroll
        for (int i = 0; i < 4; ++i) {
            zr[i] = Zt[(4 * ty + i) * 65 + j];
            yr[i] = Yt[(4 * ty + i) * 65 + j];
        }
        #pragma unroll
        for (int k = 0; k < 4; ++k) cc[k] = Ct[j * 65 + 4 * tx + k];
        #pragma unroll
        for (int i = 0; i < 4; ++i)
            #pragma unroll
            for (int k = 0; k < 4; ++k) {
                az[i][k] = fmaf(zr[i], cc[k], az[i][k]);
                ay[i][k] = fmaf(yr[i], cc[k], ay[i][k]);
            }
    }

    #pragma unroll
    for (int i = 0; i < 4; ++i) {
        int t = t0 + 4 * ty + i;
        if (t >= T) continue;
        const float4 sv = *(const float4*)&S[(size_t)t * SUBS + 4 * tx];
        float svv[4] = {sv.x, sv.y, sv.z, sv.w};
        union { bf16 h[4]; ushort4 u; } pz, pb;
        #pragma unroll
        for (int k = 0; k < 4; ++k) {
            int s = 4 * tx + k;
            pz.h[k] = __float2bfloat16(az[i][k]);
            pb.h[k] = __float2bfloat16(ay[i][k] + svv[k] + theta[s]);
        }
        *(ushort4*)&Zc  [(size_t)t * SUBS + 4 * tx] = pz.u;
        *(ushort4*)&base[(size_t)t * SUBS + 4 * tx] = pb.u;
    }
}

// ---------------------------------------------------------------------------
// Kernel 3: filtered[t,s] = sum_{d=1}^{200} kern[s][d-1] * Zc[t-d][s]
//           out = sigmoid(base + filtered) * W + V_o
// Block: 64 t-rows x 64 s. 4 waves, each wave 16 rows (lane = s).
// Rotating 16-register sliding window: per tap 2 LDS reads + 16 FMA.
// ---------------------------------------------------------------------------
__global__ __launch_bounds__(256) void k_conv(
    const bf16* __restrict__ kern_ws, const bf16* __restrict__ Zc,
    const bf16* __restrict__ base, const float* __restrict__ W,
    const float* __restrict__ Vo, float* __restrict__ out, int T)
{
    __shared__ bf16 kt[THIST * SUBS];          // 25600 B
    __shared__ bf16 wz[(64 + THIST) * SUBS];   // 33792 B
    const int tid = threadIdx.x;
    const int t0  = blockIdx.x * 64;

    {   // stage kern (vectorized ushort4 = 4 bf16)
        const ushort4* src = (const ushort4*)kern_ws;
        ushort4* dst = (ushort4*)kt;
        for (int i = tid; i < THIST * SUBS / 4; i += 256) dst[i] = src[i];
    }
    {   // stage Zc window rows [t0-200, t0+64)
        ushort4* dst = (ushort4*)wz;
        const ushort4* src = (const ushort4*)Zc;
        for (int i = tid; i < (64 + THIST) * (SUBS / 4); i += 256) {
            int r = i >> 4;
            int g = t0 - THIST + r;
            ushort4 v = make_ushort4(0, 0, 0, 0);
            if (g >= 0 && g < T) v = src[(size_t)g * (SUBS / 4) + (i & 15)];
            dst[i] = v;
        }
    }
    __syncthreads();

    const int s  = tid & 63;
    const int rt = (tid >> 6) * 16;   // this wave's first row within the tile

    float x[16], acc[16];
    #pragma unroll
    for (int r = 0; r < 16; ++r) {
        x[r]   = __bfloat162float(wz[(rt + r) * SUBS + s]);
        acc[r] = 0.f;
    }

    // dd = 0..199 maps to lag d = 200-dd; kern index = 199-dd.
    // Invariant before sub-step v: x[(v+r)&15] == wz[rt + r + dd][s].
    #pragma unroll 1
    for (int du = 0; du < 192; du += 16) {
        #pragma unroll
        for (int v = 0; v < 16; ++v) {
            const int dd = du + v;
            float kv = __bfloat162float(kt[(199 - dd) * SUBS + s]);
            #pragma unroll
            for (int r = 0; r < 16; ++r)
                acc[r] = fmaf(kv, x[(v + r) & 15], acc[r]);
            x[v] = __bfloat162float(wz[(rt + 16 + dd) * SUBS + s]);
        }
    }
    #pragma unroll
    for (int v = 0; v < 8; ++v) {
        const int dd = 192 + v;
        float kv = __bfloat162float(kt[(199 - dd) * SUBS + s]);
        #pragma unroll
        for (int r = 0; r < 16; ++r)
            acc[r] = fmaf(kv, x[(v + r) & 15], acc[r]);
        x[v] = __bfloat162float(wz[(rt + 16 + dd) * SUBS + s]);
    }

    const float wsub = W[s];
    const float vo   = Vo[0];
    #pragma unroll
    for (int r = 0; r < 16; ++r) {
        int t = t0 + rt + r;
        if (t < T) {
            float xin = __bfloat162float(base[(size_t)t * SUBS + s]) + acc[r];
            float sig = 1.0f / (1.0f + __expf(-xin));
            out[(size_t)t * SUBS + s] = fmaf(sig, wsub, vo);
        }
    }
}

// ---------------------------------------------------------------------------
extern "C" void kernel_launch(void* const* d_in, const int* in_sizes, int n_in,
                              void* d_out, int out_size, void* d_ws, size_t ws_size,
                              hipStream_t stream)
{
    const float* S     = (const float*)d_in[0];
    const float* Y     = (const float*)d_in[1];
    const float* Z     = (const float*)d_in[2];
    const float* C     = (const float*)d_in[3];
    const float* Vo    = (const float*)d_in[4];
    const float* W     = (const float*)d_in[5];
    const float* theta = (const float*)d_in[6];
    const float* K     = (const float*)d_in[7];
    const float* tau   = (const float*)d_in[8];
    const float* delta = (const float*)d_in[9];
    const int T = in_sizes[0] / SUBS;

    bf16* kern_ws = (bf16*)d_ws;                                   // 25600 B
    bf16* Zc      = (bf16*)((char*)d_ws + 32768);                  // T*64*2 B
    bf16* base    = (bf16*)((char*)d_ws + 32768 + (size_t)T * SUBS * 2);

    const int nb = (T + 63) / 64;
    k_kernels<<<(THIST * SUBS + 255) / 256, 256, 0, stream>>>(K, tau, delta, kern_ws);
    k_zc_base<<<nb, 256, 0, stream>>>(Z, Y, S, C, theta, Zc, base, T);
    k_conv<<<nb, 256, 0, stream>>>(kern_ws, Zc, base, W, Vo, (float*)d_out, T);
}

// Round 2
// 95.675 us; speedup vs baseline: 1.4071x; 1.4071x over previous
//
#include <hip/hip_runtime.h>
#include <hip/hip_bf16.h>

#define SUBS  64
#define THIST 200

using bf16 = __hip_bfloat16;
typedef __attribute__((ext_vector_type(8))) short bf16x8;
typedef __attribute__((ext_vector_type(4))) float f32x4;

__device__ inline short f2bs(float v) {
    union { bf16 h; short s; } u; u.h = __float2bfloat16(v); return u.s;
}

// ---------------------------------------------------------------------------
// Kernel 1: kern_t[k*64+s] = sum_b (t/tau_b) exp(-t/tau_b) * K[s,b]
// Stored transposed [THIST][SUBS] as bf16.
// ---------------------------------------------------------------------------
__global__ __launch_bounds__(256) void k_kernels(
    const float* __restrict__ K_spike, const float* __restrict__ tau_spike,
    const float* __restrict__ delta_spike, bf16* __restrict__ kt)
{
    int idx = blockIdx.x * 256 + threadIdx.x;
    if (idx >= THIST * SUBS) return;
    int k = idx >> 6, s = idx & 63;
    float t = fmaxf((float)k - delta_spike[s], 0.0f);
    float v = 0.0f;
    #pragma unroll
    for (int b = 0; b < 3; ++b) {
        float tau = __expf(tau_spike[b]);
        float tt  = t / tau;
        v = fmaf(tt * __expf(-tt), K_spike[s * 3 + b], v);
    }
    kt[k * SUBS + s] = __float2bfloat16(v);
}

// ---------------------------------------------------------------------------
// Kernel 2 (MFMA): Zc = Z @ C^T  (exact: 0/1 inputs),
//                  base = S + theta + Y @ C^T   (bf16)
// Block = 256 thr = 4 waves; wave w computes rows [t0+16w, +16) x all 64 cols.
// D = A(16x32) * B(32x16) via mfma_f32_16x16x32_bf16, K=64 in 2 steps.
// A[m][k]: m = lane&15, k = (lane>>4)*8+e.  B[k][n]: n = lane&15, same k.
// D: col = lane&15, row = (lane>>4)*4 + reg.
// ---------------------------------------------------------------------------
__global__ __launch_bounds__(256, 4) void k_zc_base(
    const float* __restrict__ Z, const float* __restrict__ Y,
    const float* __restrict__ S, const float* __restrict__ C,
    const float* __restrict__ theta,
    bf16* __restrict__ Zc, bf16* __restrict__ base, int T)
{
    const int tid  = threadIdx.x;
    const int lane = tid & 63;
    const int wv   = tid >> 6;
    const int lr   = lane & 15;
    const int lg   = lane >> 4;
    const int t0   = blockIdx.x * 64 + wv * 16;

    // B fragments from C:  B[j][s] = C[s][j];  n = lr+16*nt, j = ks*32+lg*8+e
    bf16x8 bfr[4][2];
    #pragma unroll
    for (int nt = 0; nt < 4; ++nt) {
        #pragma unroll
        for (int ks = 0; ks < 2; ++ks) {
            const float* p = &C[(lr + 16 * nt) * 64 + ks * 32 + lg * 8];
            float4 a = *(const float4*)p;
            float4 b = *(const float4*)(p + 4);
            bfr[nt][ks] = (bf16x8){ f2bs(a.x), f2bs(a.y), f2bs(a.z), f2bs(a.w),
                                    f2bs(b.x), f2bs(b.y), f2bs(b.z), f2bs(b.w) };
        }
    }

    // A fragments: row = t0+lr, cols ks*32+lg*8 .. +7
    const int rowA = t0 + lr;
    const bool okA = rowA < T;
    bf16x8 az[2], ay[2];
    #pragma unroll
    for (int ks = 0; ks < 2; ++ks) {
        float4 z0 = {0,0,0,0}, z1 = z0, y0 = z0, y1 = z0;
        if (okA) {
            const float* pz = &Z[(size_t)rowA * 64 + ks * 32 + lg * 8];
            const float* py = &Y[(size_t)rowA * 64 + ks * 32 + lg * 8];
            z0 = *(const float4*)pz;  z1 = *(const float4*)(pz + 4);
            y0 = *(const float4*)py;  y1 = *(const float4*)(py + 4);
        }
        az[ks] = (bf16x8){ f2bs(z0.x), f2bs(z0.y), f2bs(z0.z), f2bs(z0.w),
                           f2bs(z1.x), f2bs(z1.y), f2bs(z1.z), f2bs(z1.w) };
        ay[ks] = (bf16x8){ f2bs(y0.x), f2bs(y0.y), f2bs(y0.z), f2bs(y0.w),
                           f2bs(y1.x), f2bs(y1.y), f2bs(y1.z), f2bs(y1.w) };
    }

    f32x4 accZ[4], accY[4];
    #pragma unroll
    for (int nt = 0; nt < 4; ++nt) { accZ[nt] = (f32x4){0,0,0,0}; accY[nt] = (f32x4){0,0,0,0}; }

    #pragma unroll
    for (int nt = 0; nt < 4; ++nt) {
        #pragma unroll
        for (int ks = 0; ks < 2; ++ks) {
            accZ[nt] = __builtin_amdgcn_mfma_f32_16x16x32_bf16(az[ks], bfr[nt][ks], accZ[nt], 0, 0, 0);
            accY[nt] = __builtin_amdgcn_mfma_f32_16x16x32_bf16(ay[ks], bfr[nt][ks], accY[nt], 0, 0, 0);
        }
    }

    #pragma unroll
    for (int nt = 0; nt < 4; ++nt) {
        const int sc = lr + 16 * nt;
        const float th = theta[sc];
        #pragma unroll
        for (int r = 0; r < 4; ++r) {
            const int t = t0 + lg * 4 + r;
            if (t < T) {
                float bv = accY[nt][r] + S[(size_t)t * 64 + sc] + th;
                Zc  [(size_t)t * 64 + sc] = __float2bfloat16(accZ[nt][r]);
                base[(size_t)t * 64 + sc] = __float2bfloat16(bv);
            }
        }
    }
}

// ---------------------------------------------------------------------------
// Kernel 3: filtered[t,s] = sum_{d=1}^{200} kern[s][d-1] * Zc[t-d][s]
//           out = sigmoid(base + filtered) * W + V_o
// Block: 64 t-rows x 64 s; 4 waves x 16 rows; lane = s.
// LDS holds ONLY the Zc window (33.8 KB -> 4 blocks/CU = 16 waves/CU).
// kern taps read from global (25.6 KB, L1/L2-resident), 16 prefetched per
// unrolled group into registers.
// ---------------------------------------------------------------------------
__global__ __launch_bounds__(256, 4) void k_conv(
    const bf16* __restrict__ kern_ws, const bf16* __restrict__ Zc,
    const bf16* __restrict__ base, const float* __restrict__ W,
    const float* __restrict__ Vo, float* __restrict__ out, int T)
{
    __shared__ bf16 wz[(64 + THIST) * SUBS];   // 33792 B
    const int tid = threadIdx.x;
    const int t0  = blockIdx.x * 64;

    {   // stage Zc window rows [t0-200, t0+64)
        ushort4* dst = (ushort4*)wz;
        const ushort4* src = (const ushort4*)Zc;
        for (int i = tid; i < (64 + THIST) * (SUBS / 4); i += 256) {
            int r = i >> 4;
            int g = t0 - THIST + r;
            ushort4 v = make_ushort4(0, 0, 0, 0);
            if (g >= 0 && g < T) v = src[(size_t)g * (SUBS / 4) + (i & 15)];
            dst[i] = v;
        }
    }
    __syncthreads();

    const int s  = tid & 63;
    const int rt = (tid >> 6) * 16;   // this wave's first row within the tile

    float x[16], acc[16];
    #pragma unroll
    for (int r = 0; r < 16; ++r) {
        x[r]   = __bfloat162float(wz[(rt + r) * SUBS + s]);
        acc[r] = 0.f;
    }

    // dd = 0..199 maps to lag d = 200-dd; kern index = 199-dd.
    // Invariant before sub-step v: x[(v+r)&15] == wz[rt + r + dd][s].
    #pragma unroll 1
    for (int du = 0; du < 192; du += 16) {
        float kreg[16];
        #pragma unroll
        for (int v = 0; v < 16; ++v)
            kreg[v] = __bfloat162float(kern_ws[(199 - du - v) * SUBS + s]);
        #pragma unroll
        for (int v = 0; v < 16; ++v) {
            const float kv = kreg[v];
            #pragma unroll
            for (int r = 0; r < 16; ++r)
                acc[r] = fmaf(kv, x[(v + r) & 15], acc[r]);
            x[v] = __bfloat162float(wz[(rt + 16 + du + v) * SUBS + s]);
        }
    }
    {
        float kreg[8];
        #pragma unroll
        for (int v = 0; v < 8; ++v)
            kreg[v] = __bfloat162float(kern_ws[(7 - v) * SUBS + s]);
        #pragma unroll
        for (int v = 0; v < 8; ++v) {
            const float kv = kreg[v];
            #pragma unroll
            for (int r = 0; r < 16; ++r)
                acc[r] = fmaf(kv, x[(v + r) & 15], acc[r]);
        }
    }

    const float wsub = W[s];
    const float vo   = Vo[0];
    #pragma unroll
    for (int r = 0; r < 16; ++r) {
        int t = t0 + rt + r;
        if (t < T) {
            float xin = __bfloat162float(base[(size_t)t * SUBS + s]) + acc[r];
            float sig = 1.0f / (1.0f + __expf(-xin));
            out[(size_t)t * SUBS + s] = fmaf(sig, wsub, vo);
        }
    }
}

// ---------------------------------------------------------------------------
extern "C" void kernel_launch(void* const* d_in, const int* in_sizes, int n_in,
                              void* d_out, int out_size, void* d_ws, size_t ws_size,
                              hipStream_t stream)
{
    const float* S     = (const float*)d_in[0];
    const float* Y     = (const float*)d_in[1];
    const float* Z     = (const float*)d_in[2];
    const float* C     = (const float*)d_in[3];
    const float* Vo    = (const float*)d_in[4];
    const float* W     = (const float*)d_in[5];
    const float* theta = (const float*)d_in[6];
    const float* K     = (const float*)d_in[7];
    const float* tau   = (const float*)d_in[8];
    const float* delta = (const float*)d_in[9];
    const int T = in_sizes[0] / SUBS;

    bf16* kern_ws = (bf16*)d_ws;                                   // 25600 B
    bf16* Zc      = (bf16*)((char*)d_ws + 32768);                  // T*64*2 B
    bf16* base    = (bf16*)((char*)d_ws + 32768 + (size_t)T * SUBS * 2);

    const int nb = (T + 63) / 64;
    k_kernels<<<(THIST * SUBS + 255) / 256, 256, 0, stream>>>(K, tau, delta, kern_ws);
    k_zc_base<<<nb, 256, 0, stream>>>(Z, Y, S, C, theta, Zc, base, T);
    k_conv<<<nb, 256, 0, stream>>>(kern_ws, Zc, base, W, Vo, (float*)d_out, T);
}

// Round 3
// 82.244 us; speedup vs baseline: 1.6368x; 1.1633x over previous
//
#include <hip/hip_runtime.h>
#include <hip/hip_bf16.h>

#define SUBS  64
#define THIST 200
#define BT    128   // conv rows per block

using bf16 = __hip_bfloat16;
typedef __attribute__((ext_vector_type(8))) short bf16x8;
typedef __attribute__((ext_vector_type(4))) float f32x4;

__device__ inline short f2bs(float v) {
    union { bf16 h; short s; } u; u.h = __float2bfloat16(v); return u.s;
}

// ---------------------------------------------------------------------------
// Kernel 1: kern_t[k*64+s] = sum_b (t/tau_b) exp(-t/tau_b) * K[s,b]
// ---------------------------------------------------------------------------
__global__ __launch_bounds__(256) void k_kernels(
    const float* __restrict__ K_spike, const float* __restrict__ tau_spike,
    const float* __restrict__ delta_spike, bf16* __restrict__ kt)
{
    int idx = blockIdx.x * 256 + threadIdx.x;
    if (idx >= THIST * SUBS) return;
    int k = idx >> 6, s = idx & 63;
    float t = fmaxf((float)k - delta_spike[s], 0.0f);
    float v = 0.0f;
    #pragma unroll
    for (int b = 0; b < 3; ++b) {
        float tau = __expf(tau_spike[b]);
        float tt  = t / tau;
        v = fmaf(tt * __expf(-tt), K_spike[s * 3 + b], v);
    }
    kt[k * SUBS + s] = __float2bfloat16(v);
}

// ---------------------------------------------------------------------------
// Kernel 2 (MFMA): Zc = Z @ C^T, base = S + theta + Y @ C^T (bf16 out)
// 256 thr = 4 waves; wave wv covers rows [blk*128 + wv*32, +32) in two
// 16-row MFMA groups. Epilogue bounces accumulators through padded LDS
// so global stores are coalesced ushort4 and S loads are float4.
// ---------------------------------------------------------------------------
__global__ __launch_bounds__(256, 4) void k_zc_base(
    const float* __restrict__ Z, const float* __restrict__ Y,
    const float* __restrict__ S, const float* __restrict__ C,
    const float* __restrict__ theta,
    bf16* __restrict__ Zc, bf16* __restrict__ base, int T)
{
    __shared__ bf16 bnc[4][16 * 68];          // per-wave bounce tile, stride 68
    const int tid  = threadIdx.x;
    const int lane = tid & 63;
    const int wv   = tid >> 6;
    const int lr   = lane & 15;
    const int lg   = lane >> 4;
    const int tblk = blockIdx.x * 128 + wv * 32;
    bf16* bw = &bnc[wv][0];

    // B fragments from C: B[j][s] = C[s][j]; n = lr+16*nt, j = ks*32+lg*8+e
    bf16x8 bfr[4][2];
    #pragma unroll
    for (int nt = 0; nt < 4; ++nt) {
        #pragma unroll
        for (int ks = 0; ks < 2; ++ks) {
            const float* p = &C[(lr + 16 * nt) * 64 + ks * 32 + lg * 8];
            float4 a = *(const float4*)p;
            float4 b = *(const float4*)(p + 4);
            bfr[nt][ks] = (bf16x8){ f2bs(a.x), f2bs(a.y), f2bs(a.z), f2bs(a.w),
                                    f2bs(b.x), f2bs(b.y), f2bs(b.z), f2bs(b.w) };
        }
    }

    const float4 th = *(const float4*)&theta[lr * 4];

    #pragma unroll
    for (int g = 0; g < 2; ++g) {
        const int t0 = tblk + g * 16;

        const int rowA = t0 + lr;
        const bool okA = rowA < T;
        bf16x8 az[2], ay[2];
        #pragma unroll
        for (int ks = 0; ks < 2; ++ks) {
            float4 z0 = {0,0,0,0}, z1 = z0, y0 = z0, y1 = z0;
            if (okA) {
                const float* pz = &Z[(size_t)rowA * 64 + ks * 32 + lg * 8];
                const float* py = &Y[(size_t)rowA * 64 + ks * 32 + lg * 8];
                z0 = *(const float4*)pz;  z1 = *(const float4*)(pz + 4);
                y0 = *(const float4*)py;  y1 = *(const float4*)(py + 4);
            }
            az[ks] = (bf16x8){ f2bs(z0.x), f2bs(z0.y), f2bs(z0.z), f2bs(z0.w),
                               f2bs(z1.x), f2bs(z1.y), f2bs(z1.z), f2bs(z1.w) };
            ay[ks] = (bf16x8){ f2bs(y0.x), f2bs(y0.y), f2bs(y0.z), f2bs(y0.w),
                               f2bs(y1.x), f2bs(y1.y), f2bs(y1.z), f2bs(y1.w) };
        }

        f32x4 accZ[4], accY[4];
        #pragma unroll
        for (int nt = 0; nt < 4; ++nt) { accZ[nt] = (f32x4){0,0,0,0}; accY[nt] = (f32x4){0,0,0,0}; }
        #pragma unroll
        for (int nt = 0; nt < 4; ++nt) {
            #pragma unroll
            for (int ks = 0; ks < 2; ++ks) {
                accZ[nt] = __builtin_amdgcn_mfma_f32_16x16x32_bf16(az[ks], bfr[nt][ks], accZ[nt], 0, 0, 0);
                accY[nt] = __builtin_amdgcn_mfma_f32_16x16x32_bf16(ay[ks], bfr[nt][ks], accY[nt], 0, 0, 0);
            }
        }

        // ---- bounce Z: LDS write (conflict-free, stride 68) -> ushort4 store
        #pragma unroll
        for (int nt = 0; nt < 4; ++nt)
            #pragma unroll
            for (int r = 0; r < 4; ++r)
                bw[(lg * 4 + r) * 68 + lr + 16 * nt] = __float2bfloat16(accZ[nt][r]);
        __builtin_amdgcn_wave_barrier();
        #pragma unroll
        for (int i = 0; i < 4; ++i) {
            const int row = i * 4 + lg;
            const int t = t0 + row;
            if (t < T)
                *(ushort4*)&Zc[(size_t)t * 64 + lr * 4] =
                    *(const ushort4*)&bw[row * 68 + lr * 4];
        }
        __builtin_amdgcn_wave_barrier();

        // ---- bounce Y: LDS write -> +S+theta -> ushort4 store
        #pragma unroll
        for (int nt = 0; nt < 4; ++nt)
            #pragma unroll
            for (int r = 0; r < 4; ++r)
                bw[(lg * 4 + r) * 68 + lr + 16 * nt] = __float2bfloat16(accY[nt][r]);
        __builtin_amdgcn_wave_barrier();
        #pragma unroll
        for (int i = 0; i < 4; ++i) {
            const int row = i * 4 + lg;
            const int t = t0 + row;
            if (t < T) {
                const float4 sv = *(const float4*)&S[(size_t)t * 64 + lr * 4];
                union { bf16 h[4]; ushort4 u; } pb;
                const bf16* yb = &bw[row * 68 + lr * 4];
                pb.h[0] = __float2bfloat16(__bfloat162float(yb[0]) + sv.x + th.x);
                pb.h[1] = __float2bfloat16(__bfloat162float(yb[1]) + sv.y + th.y);
                pb.h[2] = __float2bfloat16(__bfloat162float(yb[2]) + sv.z + th.z);
                pb.h[3] = __float2bfloat16(__bfloat162float(yb[3]) + sv.w + th.w);
                *(ushort4*)&base[(size_t)t * 64 + lr * 4] = pb.u;
            }
        }
        __builtin_amdgcn_wave_barrier();
    }
}

// ---------------------------------------------------------------------------
// Kernel 3: filtered[t,s] = sum_{d=1}^{200} kern[s][d-1] * Zc[t-d][s]
//           out = sigmoid(base + filtered) * W + V_o
// 512 thr = 8 waves x 16 rows; BT=128 rows/block amortizes the 200-row halo:
// LDS 41984 B -> 3 blocks/CU = 24 waves/CU.
// ---------------------------------------------------------------------------
__global__ __launch_bounds__(512, 6) void k_conv(
    const bf16* __restrict__ kern_ws, const bf16* __restrict__ Zc,
    const bf16* __restrict__ base, const float* __restrict__ W,
    const float* __restrict__ Vo, float* __restrict__ out, int T)
{
    __shared__ bf16 wz[(BT + THIST) * SUBS];   // 41984 B
    const int tid = threadIdx.x;
    const int t0  = blockIdx.x * BT;

    {   // stage Zc window rows [t0-200, t0+BT)
        ushort4* dst = (ushort4*)wz;
        const ushort4* src = (const ushort4*)Zc;
        const int n = (BT + THIST) * (SUBS / 4);
        for (int i = tid; i < n; i += 512) {
            int r = i >> 4;
            int g = t0 - THIST + r;
            ushort4 v = make_ushort4(0, 0, 0, 0);
            if (g >= 0 && g < T) v = src[(size_t)g * (SUBS / 4) + (i & 15)];
            dst[i] = v;
        }
    }
    __syncthreads();

    const int s  = tid & 63;
    const int rt = (tid >> 6) * 16;   // this wave's first row within the tile

    float x[16], acc[16];
    #pragma unroll
    for (int r = 0; r < 16; ++r) {
        x[r]   = __bfloat162float(wz[(rt + r) * SUBS + s]);
        acc[r] = 0.f;
    }

    // dd = 0..199 maps to lag d = 200-dd; kern index = 199-dd.
    // Invariant before sub-step v: x[(v+r)&15] == wz[rt + r + dd][s].
    #pragma unroll 1
    for (int du = 0; du < 192; du += 16) {
        float kreg[16];
        #pragma unroll
        for (int v = 0; v < 16; ++v)
            kreg[v] = __bfloat162float(kern_ws[(199 - du - v) * SUBS + s]);
        #pragma unroll
        for (int v = 0; v < 16; ++v) {
            const float kv = kreg[v];
            #pragma unroll
            for (int r = 0; r < 16; ++r)
                acc[r] = fmaf(kv, x[(v + r) & 15], acc[r]);
            x[v] = __bfloat162float(wz[(rt + 16 + du + v) * SUBS + s]);
        }
    }
    {
        float kreg[8];
        #pragma unroll
        for (int v = 0; v < 8; ++v)
            kreg[v] = __bfloat162float(kern_ws[(7 - v) * SUBS + s]);
        #pragma unroll
        for (int v = 0; v < 8; ++v) {
            const float kv = kreg[v];
            #pragma unroll
            for (int r = 0; r < 16; ++r)
                acc[r] = fmaf(kv, x[(v + r) & 15], acc[r]);
        }
    }

    const float wsub = W[s];
    const float vo   = Vo[0];
    #pragma unroll
    for (int r = 0; r < 16; ++r) {
        int t = t0 + rt + r;
        if (t < T) {
            float xin = __bfloat162float(base[(size_t)t * SUBS + s]) + acc[r];
            float sig = 1.0f / (1.0f + __expf(-xin));
            out[(size_t)t * SUBS + s] = fmaf(sig, wsub, vo);
        }
    }
}

// ---------------------------------------------------------------------------
extern "C" void kernel_launch(void* const* d_in, const int* in_sizes, int n_in,
                              void* d_out, int out_size, void* d_ws, size_t ws_size,
                              hipStream_t stream)
{
    const float* S     = (const float*)d_in[0];
    const float* Y     = (const float*)d_in[1];
    const float* Z     = (const float*)d_in[2];
    const float* C     = (const float*)d_in[3];
    const float* Vo    = (const float*)d_in[4];
    const float* W     = (const float*)d_in[5];
    const float* theta = (const float*)d_in[6];
    const float* K     = (const float*)d_in[7];
    const float* tau   = (const float*)d_in[8];
    const float* delta = (const float*)d_in[9];
    const int T = in_sizes[0] / SUBS;

    bf16* kern_ws = (bf16*)d_ws;                                   // 25600 B
    bf16* Zc      = (bf16*)((char*)d_ws + 32768);                  // T*64*2 B
    bf16* base    = (bf16*)((char*)d_ws + 32768 + (size_t)T * SUBS * 2);

    k_kernels<<<(THIST * SUBS + 255) / 256, 256, 0, stream>>>(K, tau, delta, kern_ws);
    k_zc_base<<<(T + 127) / 128, 256, 0, stream>>>(Z, Y, S, C, theta, Zc, base, T);
    k_conv<<<(T + BT - 1) / BT, 512, 0, stream>>>(kern_ws, Zc, base, W, Vo, (float*)d_out, T);
}

// Round 4
// 78.174 us; speedup vs baseline: 1.7221x; 1.0521x over previous
//
#include <hip/hip_runtime.h>
#include <hip/hip_bf16.h>

#define SUBS  64
#define THIST 200
#define BT    128              // conv rows per block
#define NPAIR (THIST / 2)      // 100 kernel tap-pairs
#define WPAIR ((BT + THIST) / 2)   // 164 window pairs per s-row
#define WROW  165              // LDS words per s-row (padded, odd -> conflict-free)

typedef _Float16 h2    __attribute__((ext_vector_type(2)));
typedef _Float16 f16x8 __attribute__((ext_vector_type(8)));
typedef float    f32x4 __attribute__((ext_vector_type(4)));

union uh2 { uint u; h2 h; };

__device__ inline short f2hs(float v) {
    union { _Float16 h; short s; } u; u.h = (_Float16)v; return u.s;
}

// ---------------------------------------------------------------------------
// Kernel 1: reversed, pre-paired taps.
// krp[p*64+s] = pack(kern[s][199-2p], kern[s][198-2p]) as 2x f16.
// ---------------------------------------------------------------------------
__device__ inline float kval(int k, float del, const float* Ks, const float* tau) {
    float t = fmaxf((float)k - del, 0.0f);
    float v = 0.0f;
    #pragma unroll
    for (int b = 0; b < 3; ++b) {
        float tt = t / __expf(tau[b]);
        v = fmaf(tt * __expf(-tt), Ks[b], v);
    }
    return v;
}

__global__ __launch_bounds__(256) void k_taps(
    const float* __restrict__ K_spike, const float* __restrict__ tau_spike,
    const float* __restrict__ delta_spike, uint* __restrict__ krp)
{
    int idx = blockIdx.x * 256 + threadIdx.x;
    if (idx >= NPAIR * SUBS) return;
    int p = idx >> 6, s = idx & 63;
    float del = delta_spike[s];
    float Ks[3] = { K_spike[s*3], K_spike[s*3+1], K_spike[s*3+2] };
    float tl[3] = { tau_spike[0], tau_spike[1], tau_spike[2] };
    ushort lo = (ushort)f2hs(kval(199 - 2*p, del, Ks, tl));
    ushort hi = (ushort)f2hs(kval(198 - 2*p, del, Ks, tl));
    krp[p * 64 + s] = (uint)lo | ((uint)hi << 16);
}

// ---------------------------------------------------------------------------
// Kernel 2 (f16 MFMA): Zc = Z @ C^T, base = S + theta + Y @ C^T  (f16 out)
// ---------------------------------------------------------------------------
__global__ __launch_bounds__(256, 4) void k_zc_base(
    const float* __restrict__ Z, const float* __restrict__ Y,
    const float* __restrict__ S, const float* __restrict__ C,
    const float* __restrict__ theta,
    _Float16* __restrict__ Zc, _Float16* __restrict__ base, int T)
{
    __shared__ _Float16 bnc[4][16 * 68];      // per-wave bounce tile, stride 68
    const int tid  = threadIdx.x;
    const int lane = tid & 63;
    const int wv   = tid >> 6;
    const int lr   = lane & 15;
    const int lg   = lane >> 4;
    const int tblk = blockIdx.x * 128 + wv * 32;
    _Float16* bw = &bnc[wv][0];

    // B fragments from C: B[j][s] = C[s][j]; n = lr+16*nt, j = ks*32+lg*8+e
    f16x8 bfr[4][2];
    #pragma unroll
    for (int nt = 0; nt < 4; ++nt) {
        #pragma unroll
        for (int ks = 0; ks < 2; ++ks) {
            const float* p = &C[(lr + 16 * nt) * 64 + ks * 32 + lg * 8];
            float4 a = *(const float4*)p;
            float4 b = *(const float4*)(p + 4);
            f16x8 f;
            f[0]=(_Float16)a.x; f[1]=(_Float16)a.y; f[2]=(_Float16)a.z; f[3]=(_Float16)a.w;
            f[4]=(_Float16)b.x; f[5]=(_Float16)b.y; f[6]=(_Float16)b.z; f[7]=(_Float16)b.w;
            bfr[nt][ks] = f;
        }
    }

    const float4 th = *(const float4*)&theta[lr * 4];

    #pragma unroll
    for (int g = 0; g < 2; ++g) {
        const int t0 = tblk + g * 16;
        const int rowA = t0 + lr;
        const bool okA = rowA < T;
        f16x8 az[2], ay[2];
        #pragma unroll
        for (int ks = 0; ks < 2; ++ks) {
            float4 z0 = {0,0,0,0}, z1 = z0, y0 = z0, y1 = z0;
            if (okA) {
                const float* pz = &Z[(size_t)rowA * 64 + ks * 32 + lg * 8];
                const float* py = &Y[(size_t)rowA * 64 + ks * 32 + lg * 8];
                z0 = *(const float4*)pz;  z1 = *(const float4*)(pz + 4);
                y0 = *(const float4*)py;  y1 = *(const float4*)(py + 4);
            }
            f16x8 fz, fy;
            fz[0]=(_Float16)z0.x; fz[1]=(_Float16)z0.y; fz[2]=(_Float16)z0.z; fz[3]=(_Float16)z0.w;
            fz[4]=(_Float16)z1.x; fz[5]=(_Float16)z1.y; fz[6]=(_Float16)z1.z; fz[7]=(_Float16)z1.w;
            fy[0]=(_Float16)y0.x; fy[1]=(_Float16)y0.y; fy[2]=(_Float16)y0.z; fy[3]=(_Float16)y0.w;
            fy[4]=(_Float16)y1.x; fy[5]=(_Float16)y1.y; fy[6]=(_Float16)y1.z; fy[7]=(_Float16)y1.w;
            az[ks] = fz;  ay[ks] = fy;
        }

        f32x4 accZ[4], accY[4];
        #pragma unroll
        for (int nt = 0; nt < 4; ++nt) { accZ[nt] = (f32x4){0,0,0,0}; accY[nt] = (f32x4){0,0,0,0}; }
        #pragma unroll
        for (int nt = 0; nt < 4; ++nt) {
            #pragma unroll
            for (int ks = 0; ks < 2; ++ks) {
                accZ[nt] = __builtin_amdgcn_mfma_f32_16x16x32_f16(az[ks], bfr[nt][ks], accZ[nt], 0, 0, 0);
                accY[nt] = __builtin_amdgcn_mfma_f32_16x16x32_f16(ay[ks], bfr[nt][ks], accY[nt], 0, 0, 0);
            }
        }

        // bounce Z -> coalesced ushort4 stores
        #pragma unroll
        for (int nt = 0; nt < 4; ++nt)
            #pragma unroll
            for (int r = 0; r < 4; ++r)
                bw[(lg * 4 + r) * 68 + lr + 16 * nt] = (_Float16)accZ[nt][r];
        __builtin_amdgcn_wave_barrier();
        #pragma unroll
        for (int i = 0; i < 4; ++i) {
            const int row = i * 4 + lg;
            const int t = t0 + row;
            if (t < T)
                *(ushort4*)&Zc[(size_t)t * 64 + lr * 4] =
                    *(const ushort4*)&bw[row * 68 + lr * 4];
        }
        __builtin_amdgcn_wave_barrier();

        // bounce Y -> +S+theta -> coalesced ushort4 stores
        #pragma unroll
        for (int nt = 0; nt < 4; ++nt)
            #pragma unroll
            for (int r = 0; r < 4; ++r)
                bw[(lg * 4 + r) * 68 + lr + 16 * nt] = (_Float16)accY[nt][r];
        __builtin_amdgcn_wave_barrier();
        #pragma unroll
        for (int i = 0; i < 4; ++i) {
            const int row = i * 4 + lg;
            const int t = t0 + row;
            if (t < T) {
                const float4 sv = *(const float4*)&S[(size_t)t * 64 + lr * 4];
                union { _Float16 h[4]; ushort4 u; } pb;
                const _Float16* yb = &bw[row * 68 + lr * 4];
                pb.h[0] = (_Float16)((float)yb[0] + sv.x + th.x);
                pb.h[1] = (_Float16)((float)yb[1] + sv.y + th.y);
                pb.h[2] = (_Float16)((float)yb[2] + sv.z + th.z);
                pb.h[3] = (_Float16)((float)yb[3] + sv.w + th.w);
                *(ushort4*)&base[(size_t)t * 64 + lr * 4] = pb.u;
            }
        }
        __builtin_amdgcn_wave_barrier();
    }
}

// ---------------------------------------------------------------------------
// Kernel 3 (dot2 FIR): filtered[t,s] = sum_d kern[s][d-1] * Zc[t-d][s]
//           out = sigmoid(base + filtered) * W + V_o
// 512 thr = 8 waves x 16 rows; lane = s. LDS holds the Zc window TRANSPOSED
// ([s][time], f16, row stride 165 words) so time-pairs are one ds_read_b32.
// Inner: v_dot2_f32_f16 = 2 MACs/inst, rotating E/O pair windows.
// ---------------------------------------------------------------------------
__global__ __launch_bounds__(512, 6) void k_conv(
    const uint* __restrict__ krp, const _Float16* __restrict__ Zc,
    const _Float16* __restrict__ base, const float* __restrict__ W,
    const float* __restrict__ Vo, float* __restrict__ out, int T)
{
    __shared__ uint wzu[SUBS * WROW];          // 42240 B
    ushort* wzh = (ushort*)wzu;
    const int tid = threadIdx.x;
    const int t0  = blockIdx.x * BT;

    {   // stage + transpose Zc rows [t0-200, t0+BT): global [t][s] -> LDS [s][t]
        const ushort4* src = (const ushort4*)Zc;
        const int n = (BT + THIST) * (SUBS / 4);
        for (int i = tid; i < n; i += 512) {
            int r  = i >> 4;          // time row within window
            int c4 = i & 15;          // s-group (4 channels)
            int g  = t0 - THIST + r;
            ushort4 v = make_ushort4(0, 0, 0, 0);
            if (g >= 0 && g < T) v = src[(size_t)g * 16 + c4];
            wzh[(4 * c4 + 0) * 2 * WROW + r] = v.x;
            wzh[(4 * c4 + 1) * 2 * WROW + r] = v.y;
            wzh[(4 * c4 + 2) * 2 * WROW + r] = v.z;
            wzh[(4 * c4 + 3) * 2 * WROW + r] = v.w;
        }
    }
    __syncthreads();

    const int s   = tid & 63;
    const int wid = tid >> 6;
    const int rt  = wid * 16;         // first output row of this wave
    const int q0  = wid * 8;          // first pair index
    const uint* wp = &wzu[s * WROW];  // this lane's pair row

    float acc[16];
    #pragma unroll
    for (int r = 0; r < 16; ++r) acc[r] = 0.f;

    uint E[8], O[8];
    #pragma unroll
    for (int i = 0; i < 8; ++i) E[i] = wp[q0 + i];
    #pragma unroll
    for (int i = 0; i < 7; ++i) O[i] = __builtin_amdgcn_alignbit(E[i + 1], E[i], 16);

    // step P (=0..99): acc[2i]   += dot2(kp[P], E[q0+P+i])
    //                  acc[2i+1] += dot2(kp[P], O[q0+P+i]),  ring index (P+i)&7
    #pragma unroll 1
    for (int g = 0; g < 12; ++g) {
        uint kv[8];
        #pragma unroll
        for (int j = 0; j < 8; ++j) kv[j] = krp[(g * 8 + j) * 64 + s];
        #pragma unroll
        for (int j = 0; j < 8; ++j) {
            const uint newE = wp[q0 + g * 8 + j + 8];
            O[(j + 7) & 7] = __builtin_amdgcn_alignbit(newE, E[(j + 7) & 7], 16);
            uh2 kk; kk.u = kv[j];
            #pragma unroll
            for (int i = 0; i < 8; ++i) {
                uh2 e; e.u = E[(j + i) & 7];
                uh2 o; o.u = O[(j + i) & 7];
                acc[2 * i]     = __builtin_amdgcn_fdot2(kk.h, e.h, acc[2 * i],     false);
                acc[2 * i + 1] = __builtin_amdgcn_fdot2(kk.h, o.h, acc[2 * i + 1], false);
            }
            E[j & 7] = newE;
        }
    }
    {   // tail: pairs 96..99
        uint kv[4];
        #pragma unroll
        for (int j = 0; j < 4; ++j) kv[j] = krp[(96 + j) * 64 + s];
        #pragma unroll
        for (int j = 0; j < 4; ++j) {
            const uint newE = wp[q0 + 96 + j + 8];
            O[(j + 7) & 7] = __builtin_amdgcn_alignbit(newE, E[(j + 7) & 7], 16);
            uh2 kk; kk.u = kv[j];
            #pragma unroll
            for (int i = 0; i < 8; ++i) {
                uh2 e; e.u = E[(j + i) & 7];
                uh2 o; o.u = O[(j + i) & 7];
                acc[2 * i]     = __builtin_amdgcn_fdot2(kk.h, e.h, acc[2 * i],     false);
                acc[2 * i + 1] = __builtin_amdgcn_fdot2(kk.h, o.h, acc[2 * i + 1], false);
            }
            E[j & 7] = newE;
        }
    }

    const float wsub = W[s];
    const float vo   = Vo[0];
    #pragma unroll
    for (int r = 0; r < 16; ++r) {
        int t = t0 + rt + r;
        if (t < T) {
            float xin = (float)base[(size_t)t * SUBS + s] + acc[r];
            float sig = 1.0f / (1.0f + __expf(-xin));
            out[(size_t)t * SUBS + s] = fmaf(sig, wsub, vo);
        }
    }
}

// ---------------------------------------------------------------------------
extern "C" void kernel_launch(void* const* d_in, const int* in_sizes, int n_in,
                              void* d_out, int out_size, void* d_ws, size_t ws_size,
                              hipStream_t stream)
{
    const float* S     = (const float*)d_in[0];
    const float* Y     = (const float*)d_in[1];
    const float* Z     = (const float*)d_in[2];
    const float* C     = (const float*)d_in[3];
    const float* Vo    = (const float*)d_in[4];
    const float* W     = (const float*)d_in[5];
    const float* theta = (const float*)d_in[6];
    const float* K     = (const float*)d_in[7];
    const float* tau   = (const float*)d_in[8];
    const float* delta = (const float*)d_in[9];
    const int T = in_sizes[0] / SUBS;

    uint*      krp  = (uint*)d_ws;                                  // 25600 B
    _Float16*  Zc   = (_Float16*)((char*)d_ws + 32768);             // T*64*2 B
    _Float16*  base = (_Float16*)((char*)d_ws + 32768 + (size_t)T * SUBS * 2);

    k_taps<<<(NPAIR * SUBS + 255) / 256, 256, 0, stream>>>(K, tau, delta, krp);
    k_zc_base<<<(T + 127) / 128, 256, 0, stream>>>(Z, Y, S, C, theta, Zc, base, T);
    k_conv<<<(T + BT - 1) / BT, 512, 0, stream>>>(krp, Zc, base, W, Vo, (float*)d_out, T);
}